// Round 1
// baseline (340.328 us; speedup 1.0000x reference)
//
#include <hip/hip_runtime.h>

// TemporalShift: x (nt=64, c=256, h=56, w=56) fp32, t=8 segments, fold=c/8=32.
//   c in [0,32):   out[n,t] = x[n,t+1]  (zero at t==7)
//   c in [32,64):  out[n,t] = x[n,t-1]  (zero at t==0)
//   c in [64,256): out[n,t] = x[n,t]
// Shift along t is a constant linear offset of +-C*H*W elements.
// Pure memory-bound copy; float4 vectorized, grid-stride.

#define HW4        784        // (56*56)/4 float4 per (nt,c) plane
#define CCH        256        // channels
#define FOLD       32         // c/8
#define PLANE4     (CCH * HW4) // float4 per nt index = 200704

__global__ __launch_bounds__(256) void TemporalShift_50242527428854_kernel(
    const float4* __restrict__ in, float4* __restrict__ out, int total4) {
    const float4 zero = make_float4(0.f, 0.f, 0.f, 0.f);
    for (int i = blockIdx.x * blockDim.x + threadIdx.x; i < total4;
         i += gridDim.x * blockDim.x) {
        int plane = i / HW4;          // (nt*256 + c)
        int c     = plane % CCH;
        int nt    = plane / CCH;
        int t     = nt & 7;           // nt = n*8 + t
        float4 v;
        if (c < FOLD) {
            v = (t == 7) ? zero : in[i + PLANE4];
        } else if (c < 2 * FOLD) {
            v = (t == 0) ? zero : in[i - PLANE4];
        } else {
            v = in[i];
        }
        out[i] = v;
    }
}

extern "C" void kernel_launch(void* const* d_in, const int* in_sizes, int n_in,
                              void* d_out, int out_size, void* d_ws, size_t ws_size,
                              hipStream_t stream) {
    const float4* in  = (const float4*)d_in[0];
    float4*       out = (float4*)d_out;
    int total4 = out_size / 4;                 // 12,845,056 float4
    int blocks = (total4 + 255) / 256;
    if (blocks > 2048) blocks = 2048;          // grid-stride; 256 CU * 8 blocks
    TemporalShift_50242527428854_kernel<<<blocks, 256, 0, stream>>>(in, out, total4);
}

// Round 3
// 320.398 us; speedup vs baseline: 1.0622x; 1.0622x over previous
//
#include <hip/hip_runtime.h>

// TemporalShift: x (nt=64, c=256, h=56, w=56) fp32, t=8 segments, fold=c/8=32.
//   c in [0,32):   out[n,t] = x[n,t+1]  (zero at t==7)
//   c in [32,64):  out[n,t] = x[n,t-1]  (zero at t==0)
//   c in [64,256): out[n,t] = x[n,t]
// Pure memory-bound permuted copy. R1 lesson: MLP=1 per wave capped us at
// 1.68 TB/s; this version issues 4 independent 16B loads per thread
// (batched before use), launches the exact full grid (no grid-stride), and
// uses nontemporal stores so the output stream doesn't evict the input
// from the 256 MB L3. R2 lesson: __builtin_nontemporal_store needs a
// clang ext_vector type, not HIP's float4 class.

typedef float f32x4 __attribute__((ext_vector_type(4)));

#define HW4        784          // (56*56)/4 vec4 per (nt,c) plane
#define CCH        256          // channels
#define FOLD       32           // c/8
#define PLANE4     (CCH * HW4)  // vec4 per nt index = 200704
#define ELEMS_PER_BLOCK 1024    // 256 threads x 4 vec4

__global__ __launch_bounds__(256) void TemporalShift_50242527428854_kernel(
    const f32x4* __restrict__ in, f32x4* __restrict__ out) {
    const int base = blockIdx.x * ELEMS_PER_BLOCK + threadIdx.x;

    int  idx[4];
    int  src[4];
    bool zf[4];

    // Phase 1: compute all addresses (no memory ops yet)
#pragma unroll
    for (int k = 0; k < 4; ++k) {
        const int i = base + k * 256;       // 64 consecutive lanes -> coalesced
        idx[k] = i;
        const int plane = i / HW4;          // nt*256 + c  (magic-mul, cheap)
        const int c     = plane % CCH;
        const int t     = (plane / CCH) & 7;
        int  s = i;
        bool z = false;
        if (c < FOLD) {                     // shift from t+1
            if (t == 7) z = true; else s = i + PLANE4;
        } else if (c < 2 * FOLD) {          // shift from t-1
            if (t == 0) z = true; else s = i - PLANE4;
        }
        src[k] = s;                         // z-case keeps s=i (safe, in-bounds)
        zf[k]  = z;
    }

    // Phase 2: issue all 4 loads back-to-back (4 outstanding per thread)
    f32x4 v[4];
#pragma unroll
    for (int k = 0; k < 4; ++k) v[k] = __builtin_nontemporal_load(&in[src[k]]);

    // Phase 3: select zeros, nontemporal store
    const f32x4 zero = {0.f, 0.f, 0.f, 0.f};
#pragma unroll
    for (int k = 0; k < 4; ++k) {
        const f32x4 r = zf[k] ? zero : v[k];
        __builtin_nontemporal_store(r, &out[idx[k]]);
    }
}

extern "C" void kernel_launch(void* const* d_in, const int* in_sizes, int n_in,
                              void* d_out, int out_size, void* d_ws, size_t ws_size,
                              hipStream_t stream) {
    const f32x4* in  = (const f32x4*)d_in[0];
    f32x4*       out = (f32x4*)d_out;
    const int total4 = out_size / 4;                       // 12,845,056
    const int blocks = total4 / ELEMS_PER_BLOCK;           // 12,544 exact
    TemporalShift_50242527428854_kernel<<<blocks, 256, 0, stream>>>(in, out);
}